// Round 1
// baseline (521.458 us; speedup 1.0000x reference)
//
#include <hip/hip_runtime.h>
#include <hip/hip_bf16.h>

#define IN_F 128
#define OUT_F 16
#define NEG_SLOPE 0.2f

// ---------------------------------------------------------------------------
// Projection: hW = h @ W^T  [N,16], el = hW @ a_l^T, er = hW @ a_r^T
// 16 threads per node (one per output feature); W (16x128 = 8KB) in LDS.
// ---------------------------------------------------------------------------
__global__ __launch_bounds__(256) void proj_kernel(
    const float* __restrict__ h, const float* __restrict__ W,
    const float* __restrict__ a_l, const float* __restrict__ a_r,
    float* __restrict__ hW, float* __restrict__ el, float* __restrict__ er,
    int N) {
  __shared__ float Ws[OUT_F * IN_F];
  for (int i = threadIdx.x; i < OUT_F * IN_F; i += blockDim.x) Ws[i] = W[i];
  __syncthreads();

  int gid = blockIdx.x * blockDim.x + threadIdx.x;
  int node = gid >> 4;
  int feat = gid & 15;
  if (node >= N) return;

  const float4* hrow = (const float4*)(h + (size_t)node * IN_F);
  const float4* wrow = (const float4*)(&Ws[feat * IN_F]);
  float acc = 0.f;
#pragma unroll
  for (int k = 0; k < IN_F / 4; ++k) {
    float4 hv = hrow[k];
    float4 wv = wrow[k];
    acc += hv.x * wv.x + hv.y * wv.y + hv.z * wv.z + hv.w * wv.w;
  }
  hW[node * OUT_F + feat] = acc;

  float vl = acc * a_l[feat];
  float vr = acc * a_r[feat];
#pragma unroll
  for (int off = 8; off; off >>= 1) {
    vl += __shfl_down(vl, off, 16);
    vr += __shfl_down(vr, off, 16);
  }
  if (feat == 0) {
    el[node] = vl;
    er[node] = vr;
  }
}

// ---------------------------------------------------------------------------
// Edge pass 1: esum[dst] += exp(leaky_relu(el[src] + er[dst]))
// (max-subtraction skipped: mathematically identical softmax, logits are small)
// ---------------------------------------------------------------------------
__global__ __launch_bounds__(256) void edge_sum_kernel(
    const int* __restrict__ src, const int* __restrict__ dst,
    const float* __restrict__ el, const float* __restrict__ er,
    float* __restrict__ esum, int E) {
  int e = blockIdx.x * blockDim.x + threadIdx.x;
  if (e >= E) return;
  int s = src[e];
  int d = dst[e];
  float x = el[s] + er[d];
  x = x > 0.f ? x : NEG_SLOPE * x;
  atomicAdd(&esum[d], __expf(x));
}

// ---------------------------------------------------------------------------
// Edge pass 2: out[dst] += hW[src] * alpha ;  16 lanes per edge (one per feat)
// ---------------------------------------------------------------------------
__global__ __launch_bounds__(256) void edge_agg_kernel(
    const int* __restrict__ src, const int* __restrict__ dst,
    const float* __restrict__ el, const float* __restrict__ er,
    const float* __restrict__ esum, const float* __restrict__ hW,
    float* __restrict__ out, int E) {
  int gid = blockIdx.x * blockDim.x + threadIdx.x;
  int e = gid >> 4;
  int f = gid & 15;
  if (e >= E) return;
  int s = src[e];
  int d = dst[e];
  float x = el[s] + er[d];
  x = x > 0.f ? x : NEG_SLOPE * x;
  float alpha = __expf(x) / fmaxf(esum[d], 1e-16f);
  atomicAdd(&out[d * OUT_F + f], hW[s * OUT_F + f] * alpha);
}

extern "C" void kernel_launch(void* const* d_in, const int* in_sizes, int n_in,
                              void* d_out, int out_size, void* d_ws, size_t ws_size,
                              hipStream_t stream) {
  const float* h   = (const float*)d_in[0];
  const int*   src = (const int*)d_in[1];
  const int*   dst = (const int*)d_in[2];
  const float* W   = (const float*)d_in[3];
  const float* a_l = (const float*)d_in[4];
  const float* a_r = (const float*)d_in[5];
  float* out = (float*)d_out;

  const int N = in_sizes[0] / IN_F;
  const int E = in_sizes[1];

  float* ws   = (float*)d_ws;
  float* hW   = ws;                 // N*16
  float* el   = hW + (size_t)N * OUT_F;  // N
  float* er   = el + N;             // N
  float* esum = er + N;             // N

  hipMemsetAsync(d_out, 0, (size_t)out_size * sizeof(float), stream);
  hipMemsetAsync(esum, 0, (size_t)N * sizeof(float), stream);

  {
    int total = N * OUT_F;
    int blocks = (total + 255) / 256;
    proj_kernel<<<blocks, 256, 0, stream>>>(h, W, a_l, a_r, hW, el, er, N);
  }
  {
    int blocks = (E + 255) / 256;
    edge_sum_kernel<<<blocks, 256, 0, stream>>>(src, dst, el, er, esum, E);
  }
  {
    long long total = (long long)E * OUT_F;
    int blocks = (int)((total + 255) / 256);
    edge_agg_kernel<<<blocks, 256, 0, stream>>>(src, dst, el, er, esum, hW, out, E);
  }
}